// Round 4
// baseline (190.508 us; speedup 1.0000x reference)
//
#include <hip/hip_runtime.h>

#define BATCH 512
#define GRID_N 25
#define NODES 625            // 25*25
#define BN (BATCH * NODES)   // 320000
#define NTILES (BN / 16)     // 20000
#define F 66
#define D 64
#define TILE_FLOATS (16 * F)         // 1056 floats = 4224 B, 16B-aligned stride
#define WPB 4                        // waves per block
#define TPW 2                        // tiles per wave
#define NBLOCKS (NTILES / (WPB * TPW))   // 2500

typedef short bf16x8 __attribute__((ext_vector_type(8)));  // 8 bf16 bits (4 VGPRs)
typedef float f32x4  __attribute__((ext_vector_type(4)));

// fp32 -> bf16 bits, round-to-nearest-even
__device__ __forceinline__ short f2bf(float f) {
    union { float f; unsigned u; } c; c.f = f;
    unsigned r = c.u + 0x7fffu + ((c.u >> 16) & 1u);
    return (short)(r >> 16);
}

// async global->LDS, 16 B per lane. LDS dest is wave-uniform base + lane*16
// (guide §5 caveat): pass per-lane pointers consistent with that layout.
__device__ __forceinline__ void stage16(const float* g, float* l) {
    __builtin_amdgcn_global_load_lds(
        (const __attribute__((address_space(1))) float*)g,
        (__attribute__((address_space(3))) float*)l,
        16, 0, 0);
}

// ---------------- Kernel A (MFMA, LDS-staged): h = x@Wfc^T+bfc ; u=h.Wat[0:64], v=h.Wat[64:128]
// One wave per 16-node tile, 2 tiles per wave staged concurrently.
// A[m=lane&15][k=quad*8+j], B[k][n=lane&15]=Wfc[n][k], C/D: row=quad*4+reg, col=lane&15.
__global__ __launch_bounds__(256, 4) void fc_mfma(
    const float* __restrict__ x, const float* __restrict__ Wfc,
    const float* __restrict__ bfc, const float* __restrict__ Wat,
    float* __restrict__ hout, float* __restrict__ u, float* __restrict__ v)
{
    const int tid  = threadIdx.x;
    const int lane = tid & 63;
    const int wid  = tid >> 6;
    const int l15  = lane & 15;
    const int quad = lane >> 4;
    const int gw   = blockIdx.x * WPB + wid;        // 0..9999

    __shared__ float smem[WPB * TPW * TILE_FLOATS]; // 33792 B
    float* sbuf = smem + wid * (TPW * TILE_FLOATS); // wave-private, 16B-aligned

    const int tile0 = gw * TPW;

    // ---- issue async staging for both tiles (coalesced, 5 instrs each) ----
#pragma unroll
    for (int t = 0; t < TPW; ++t) {
        const float* g = x + (size_t)(tile0 + t) * TILE_FLOATS;
        float* s = sbuf + t * TILE_FLOATS;
#pragma unroll
        for (int i = 0; i < 4; ++i)
            stage16(g + i * 256 + lane * 4, s + i * 256 + lane * 4);
        if (lane < 8)                                    // 4224-4096 = 128 B tail
            stage16(g + 1024 + lane * 4, s + 1024 + lane * 4);
    }

    // ---- per-wave constants (VMEM, overlap with staging) ----
    bf16x8 bfrag[4][3];
#pragma unroll
    for (int t = 0; t < 4; ++t) {
        const float* wr = Wfc + (t * 16 + l15) * F;
#pragma unroll
        for (int c = 0; c < 2; ++c) {
            bf16x8 fr;
#pragma unroll
            for (int j = 0; j < 8; ++j) fr[j] = f2bf(wr[c * 32 + quad * 8 + j]);
            bfrag[t][c] = fr;
        }
        bf16x8 z = {0, 0, 0, 0, 0, 0, 0, 0};            // K-chunk 2: only k=64,65 live
        if (quad == 0) { z[0] = f2bf(wr[64]); z[1] = f2bf(wr[65]); }
        bfrag[t][2] = z;
    }
    float bft[4], wa1[4], wa2[4];
#pragma unroll
    for (int t = 0; t < 4; ++t) {
        bft[t] = bfc[t * 16 + l15];
        wa1[t] = Wat[t * 16 + l15];
        wa2[t] = Wat[64 + t * 16 + l15];
    }

    // wait for all VMEM (staging + weights); wave-private buffers -> no barrier
    __builtin_amdgcn_s_waitcnt(0x0F70);   // vmcnt(0) only
    asm volatile("" ::: "memory");

#pragma unroll
    for (int t = 0; t < TPW; ++t) {
        const int bn0 = (tile0 + t) * 16;
        const float2* row = (const float2*)(sbuf + t * TILE_FLOATS) + l15 * (F / 2);

        // ---- A fragments from LDS (float2 reads, 8B-aligned) ----
        float xv[16];
#pragma unroll
        for (int c = 0; c < 2; ++c)
#pragma unroll
            for (int j2 = 0; j2 < 4; ++j2) {
                const float2 p = row[c * 16 + quad * 4 + j2];
                xv[c * 8 + j2 * 2]     = p.x;
                xv[c * 8 + j2 * 2 + 1] = p.y;
            }
        bf16x8 afrag[3];
#pragma unroll
        for (int c = 0; c < 2; ++c) {
            bf16x8 fr;
#pragma unroll
            for (int j = 0; j < 8; ++j) fr[j] = f2bf(xv[c * 8 + j]);
            afrag[c] = fr;
        }
        {
            bf16x8 z = {0, 0, 0, 0, 0, 0, 0, 0};
            if (quad == 0) {
                const float2 p = row[32];               // floats 64,65
                z[0] = f2bf(p.x); z[1] = f2bf(p.y);
            }
            afrag[2] = z;
        }

        // ---- MFMA: 4 N-tiles x 3 K-chunks ----
        f32x4 acc[4] = {{0,0,0,0},{0,0,0,0},{0,0,0,0},{0,0,0,0}};
#pragma unroll
        for (int nt = 0; nt < 4; ++nt)
#pragma unroll
            for (int c = 0; c < 3; ++c)
                acc[nt] = __builtin_amdgcn_mfma_f32_16x16x32_bf16(afrag[c], bfrag[nt][c], acc[nt], 0, 0, 0);

        // ---- epilogue: h store + u/v dots ----
        float pu[4] = {0, 0, 0, 0}, pv[4] = {0, 0, 0, 0};
#pragma unroll
        for (int nt = 0; nt < 4; ++nt) {
#pragma unroll
            for (int r = 0; r < 4; ++r) {
                const float h = acc[nt][r] + bft[nt];
                hout[(size_t)(bn0 + quad * 4 + r) * D + nt * 16 + l15] = h;
                pu[r] = fmaf(h, wa1[nt], pu[r]);
                pv[r] = fmaf(h, wa2[nt], pv[r]);
            }
        }
#pragma unroll
        for (int off = 8; off > 0; off >>= 1) {
#pragma unroll
            for (int r = 0; r < 4; ++r) {
                pu[r] += __shfl_xor(pu[r], off, 64);
                pv[r] += __shfl_xor(pv[r], off, 64);
            }
        }
        if (l15 == 0) {
#pragma unroll
            for (int r = 0; r < 4; ++r) {
                u[bn0 + quad * 4 + r] = pu[r];
                v[bn0 + quad * 4 + r] = pv[r];
            }
        }
    }
}

// ---------------- Kernel B: s[k] = leaky(u[n] + v[neigh(n,k)] + b_at); softmax over k
__global__ __launch_bounds__(256) void attn_kernel(
    const float* __restrict__ u, const float* __restrict__ v,
    const float* __restrict__ bat, float* __restrict__ wout)
{
    const int bn = blockIdx.x * blockDim.x + threadIdx.x;
    if (bn >= BN) return;

    const int b   = bn / NODES;
    const int n   = bn - b * NODES;
    const int row = n / GRID_N;
    const int col = n - row * GRID_N;
    const int r0 = row + (row == 0) - (row == GRID_N - 1);
    const int c0 = col + (col == 0) - (col == GRID_N - 1);

    const float* vb = v + b * NODES;
    const float u0 = u[bn] + bat[0];

    float s[9];
#pragma unroll
    for (int k = 0; k < 9; ++k) {
        const int nr = r0 + (k / 3) - 1;
        const int nc = c0 + (k % 3) - 1;
        const float t = u0 + vb[nr * GRID_N + nc];
        s[k] = (t >= 0.0f) ? t : 0.01f * t;
    }
    float m = s[0];
#pragma unroll
    for (int k = 1; k < 9; ++k) m = fmaxf(m, s[k]);
    float sum = 0.0f;
#pragma unroll
    for (int k = 0; k < 9; ++k) { s[k] = __expf(s[k] - m); sum += s[k]; }
    const float inv = 1.0f / sum;
#pragma unroll
    for (int k = 0; k < 9; ++k) wout[(size_t)bn * 9 + k] = s[k] * inv;
}

extern "C" void kernel_launch(void* const* d_in, const int* in_sizes, int n_in,
                              void* d_out, int out_size, void* d_ws, size_t ws_size,
                              hipStream_t stream)
{
    const float* x   = (const float*)d_in[0];
    const float* Wfc = (const float*)d_in[1];
    const float* bfc = (const float*)d_in[2];
    const float* Wat = (const float*)d_in[3];
    const float* bat = (const float*)d_in[4];

    float* hout = (float*)d_out;                       // [B, N, 64]
    float* wout = (float*)d_out + (size_t)BN * D;      // [B, N, 9]
    float* u = (float*)d_ws;                           // [B*N]
    float* v = u + BN;                                 // [B*N]

    fc_mfma<<<NBLOCKS, 256, 0, stream>>>(x, Wfc, bfc, Wat, hout, u, v);
    attn_kernel<<<(BN + 255) / 256, 256, 0, stream>>>(u, v, bat, wout);
}

// Round 5
// 175.985 us; speedup vs baseline: 1.0825x; 1.0825x over previous
//
#include <hip/hip_runtime.h>

#define BATCH 512
#define GRID_N 25
#define NODES 625            // 25*25
#define BN (BATCH * NODES)   // 320000
#define NTILES (BN / 16)     // 20000
#define F 66
#define D 64
#define WPB 4                // waves per block
#define TPW 2                // tiles per wave
#define NBLOCKS (NTILES / (WPB * TPW))   // 2500

typedef short bf16x8 __attribute__((ext_vector_type(8)));  // 8 bf16 bits (4 VGPRs)
typedef float f32x4  __attribute__((ext_vector_type(4)));

// fp32 -> bf16 bits, round-to-nearest-even
__device__ __forceinline__ short f2bf(float f) {
    union { float f; unsigned u; } c; c.f = f;
    unsigned r = c.u + 0x7fffu + ((c.u >> 16) & 1u);
    return (short)(r >> 16);
}

// ---------------- Kernel A (MFMA, register-prefetched):
// h = x@Wfc^T+bfc ; u=h.Wat[0:64] ; v=h.Wat[64:128]
// One wave per 16-node tile, TPW tiles per wave, ALL x-loads issued up front.
// A[m=lane&15][k=quad*8+j], B[k][n=lane&15]=Wfc[n][k], C/D row=quad*4+reg, col=lane&15.
__global__ __launch_bounds__(256, 3) void fc_mfma(
    const float* __restrict__ x, const float* __restrict__ Wfc,
    const float* __restrict__ bfc, const float* __restrict__ Wat,
    float* __restrict__ hout, float* __restrict__ u, float* __restrict__ v)
{
    const int tid  = threadIdx.x;
    const int lane = tid & 63;
    const int wid  = tid >> 6;
    const int l15  = lane & 15;
    const int quad = lane >> 4;
    const int gw   = blockIdx.x * WPB + wid;        // 0..9999
    const int tile0 = gw * TPW;

    __shared__ float smem[WPB * 256 * 4];           // 4 KB per wave (transpose buf)
    float* tbuf = smem + wid * 1024;

    // ---- issue x loads for BOTH tiles into VGPRs (float2, 8B-aligned) ----
    // row floats: (tile0+t)*1056 + l15*66  (both even -> float2-safe)
    float2 xb[TPW][9];
#pragma unroll
    for (int t = 0; t < TPW; ++t) {
        const float2* rp = (const float2*)x + (size_t)(tile0 + t) * 528 + l15 * 33;
#pragma unroll
        for (int j2 = 0; j2 < 4; ++j2) xb[t][j2]     = rp[quad * 4 + j2];       // k 0..31
#pragma unroll
        for (int j2 = 0; j2 < 4; ++j2) xb[t][4 + j2] = rp[16 + quad * 4 + j2];  // k 32..63
        if (quad == 0) xb[t][8] = rp[32];                                        // k 64,65
    }

    // ---- per-wave weight fragments (float2 loads, overlap with x latency) ----
    bf16x8 bfrag[4][3];
#pragma unroll
    for (int t = 0; t < 4; ++t) {
        const float2* wr = (const float2*)Wfc + (t * 16 + l15) * 33;
#pragma unroll
        for (int c = 0; c < 2; ++c) {
            bf16x8 fr;
#pragma unroll
            for (int j2 = 0; j2 < 4; ++j2) {
                const float2 p = wr[c * 16 + quad * 4 + j2];
                fr[j2 * 2]     = f2bf(p.x);
                fr[j2 * 2 + 1] = f2bf(p.y);
            }
            bfrag[t][c] = fr;
        }
        bf16x8 z = {0, 0, 0, 0, 0, 0, 0, 0};        // K-chunk 2: only k=64,65 live
        if (quad == 0) {
            const float2 p = wr[32];
            z[0] = f2bf(p.x); z[1] = f2bf(p.y);
        }
        bfrag[t][2] = z;
    }
    float bft[4], wa1[4], wa2[4];
#pragma unroll
    for (int t = 0; t < 4; ++t) {
        bft[t] = bfc[t * 16 + l15];
        wa1[t] = Wat[t * 16 + l15];
        wa2[t] = Wat[64 + t * 16 + l15];
    }

#pragma unroll
    for (int t = 0; t < TPW; ++t) {
        const int bn0 = (tile0 + t) * 16;

        // ---- A fragments from the prefetched registers ----
        bf16x8 afrag[3];
#pragma unroll
        for (int c = 0; c < 2; ++c) {
            bf16x8 fr;
#pragma unroll
            for (int j2 = 0; j2 < 4; ++j2) {
                const float2 p = xb[t][c * 4 + j2];
                fr[j2 * 2]     = f2bf(p.x);
                fr[j2 * 2 + 1] = f2bf(p.y);
            }
            afrag[c] = fr;
        }
        {
            bf16x8 z = {0, 0, 0, 0, 0, 0, 0, 0};
            if (quad == 0) { z[0] = f2bf(xb[t][8].x); z[1] = f2bf(xb[t][8].y); }
            afrag[2] = z;
        }

        // ---- MFMA: 4 N-tiles x 3 K-chunks ----
        f32x4 acc[4] = {{0,0,0,0},{0,0,0,0},{0,0,0,0},{0,0,0,0}};
#pragma unroll
        for (int nt = 0; nt < 4; ++nt)
#pragma unroll
            for (int c = 0; c < 3; ++c)
                acc[nt] = __builtin_amdgcn_mfma_f32_16x16x32_bf16(afrag[c], bfrag[nt][c], acc[nt], 0, 0, 0);

        // ---- epilogue: bias, u/v partials, LDS transpose, coalesced store ----
        float pu[4] = {0, 0, 0, 0}, pv[4] = {0, 0, 0, 0};
#pragma unroll
        for (int nt = 0; nt < 4; ++nt) {
#pragma unroll
            for (int r = 0; r < 4; ++r) {
                const float h = acc[nt][r] + bft[nt];
                tbuf[(quad * 4 + r) * 64 + nt * 16 + l15] = h;   // h_tile[node][ch]
                pu[r] = fmaf(h, wa1[nt], pu[r]);
                pv[r] = fmaf(h, wa2[nt], pv[r]);
            }
        }
#pragma unroll
        for (int off = 8; off > 0; off >>= 1) {
#pragma unroll
            for (int r = 0; r < 4; ++r) {
                pu[r] += __shfl_xor(pu[r], off, 64);
                pv[r] += __shfl_xor(pv[r], off, 64);
            }
        }
        if (l15 == 0) {
#pragma unroll
            for (int r = 0; r < 4; ++r) {
                u[bn0 + quad * 4 + r] = pu[r];
                v[bn0 + quad * 4 + r] = pv[r];
            }
        }
        // wave-private transpose buffer -> no barrier; compiler inserts lgkmcnt
        float4* dst = (float4*)(hout + (size_t)bn0 * D);
        const float4* src = (const float4*)tbuf;
#pragma unroll
        for (int i = 0; i < 4; ++i)
            dst[i * 64 + lane] = src[i * 64 + lane];   // 1 KB contiguous per instr
    }
}

// ---------------- Kernel B: s[k] = leaky(u[n] + v[neigh(n,k)] + b_at); softmax over k
// wave-cooperative coalesced output via wave-private LDS
__global__ __launch_bounds__(256) void attn_kernel(
    const float* __restrict__ u, const float* __restrict__ v,
    const float* __restrict__ bat, float* __restrict__ wout)
{
    __shared__ float sw[256 * 9];
    const int tid  = threadIdx.x;
    const int lane = tid & 63;
    const int wid  = tid >> 6;
    const int bn   = blockIdx.x * 256 + tid;        // BN = 1250 * 256 exactly

    const int b   = bn / NODES;
    const int n   = bn - b * NODES;
    const int row = n / GRID_N;
    const int col = n - row * GRID_N;
    // reference's edge clamp: shift whole 3x3 window inward at the borders
    const int r0 = row + (row == 0) - (row == GRID_N - 1);
    const int c0 = col + (col == 0) - (col == GRID_N - 1);

    const float* vb = v + b * NODES;
    const float u0 = u[bn] + bat[0];

    float s[9];
#pragma unroll
    for (int k = 0; k < 9; ++k) {
        const int nr = r0 + (k / 3) - 1;
        const int nc = c0 + (k % 3) - 1;
        const float t = u0 + vb[nr * GRID_N + nc];
        s[k] = (t >= 0.0f) ? t : 0.01f * t;
    }
    float m = s[0];
#pragma unroll
    for (int k = 1; k < 9; ++k) m = fmaxf(m, s[k]);
    float sum = 0.0f;
#pragma unroll
    for (int k = 0; k < 9; ++k) { s[k] = __expf(s[k] - m); sum += s[k]; }
    const float inv = 1.0f / sum;

    float* ws = sw + wid * 576;                     // wave-private 2304 B
#pragma unroll
    for (int k = 0; k < 9; ++k) ws[lane * 9 + k] = s[k] * inv;

    // 576 floats = 144 float4 per wave, fully coalesced
    float4* dst = (float4*)(wout + (size_t)(blockIdx.x * 256 + wid * 64) * 9);
    const float4* src = (const float4*)ws;
    dst[lane]      = src[lane];
    dst[64 + lane] = src[64 + lane];
    if (lane < 16) dst[128 + lane] = src[128 + lane];
}

extern "C" void kernel_launch(void* const* d_in, const int* in_sizes, int n_in,
                              void* d_out, int out_size, void* d_ws, size_t ws_size,
                              hipStream_t stream)
{
    const float* x   = (const float*)d_in[0];
    const float* Wfc = (const float*)d_in[1];
    const float* bfc = (const float*)d_in[2];
    const float* Wat = (const float*)d_in[3];
    const float* bat = (const float*)d_in[4];

    float* hout = (float*)d_out;                       // [B, N, 64]
    float* wout = (float*)d_out + (size_t)BN * D;      // [B, N, 9]
    float* u = (float*)d_ws;                           // [B*N]
    float* v = u + BN;                                 // [B*N]

    fc_mfma<<<NBLOCKS, 256, 0, stream>>>(x, Wfc, bfc, Wat, hout, u, v);
    attn_kernel<<<BN / 256, 256, 0, stream>>>(u, v, bat, wout);
}